// Round 7
// baseline (14266.655 us; speedup 1.0000x reference)
//
#include <hip/hip_runtime.h>
#include <hip/hip_fp16.h>

#define BB 16
#define TT 1024
#define DD 1024
#define SS 512
#define KK2 2048  // per-batch exchange state: [ctx | h] bf16

#define NBLK 128
#define NTHR 512

// d_out layout (floats): context [0,16384) | alignment [16384, 8404992) | termination [8404992,+16)
#define OUT_ALIGN 16384
#define OUT_TERM  8404992

typedef __attribute__((ext_vector_type(8))) short short8;     // 8 bf16 (4 VGPRs)
typedef __attribute__((ext_vector_type(4))) float floatx4;    // MFMA C/D + vec loads
typedef __attribute__((ext_vector_type(2))) _Float16 half2v;  // v_dot2 operand

struct KParams {
  const float* x;      // (B,T,D) fp32
  const float* mem;    // (B,S,D) fp32
  const int*   lens;
  const float* W_ih;   // (4D, 2D)
  const float* W_hh;   // (4D, D)
  const float* b_ih;
  const float* b_hh;
  const float* Wg_w;   // (48, D)
  const float* Wg_b;
  float* out;
  unsigned* bar;        // [0]=release word; [64+blk*32]=arrival flags (zeroed each call)
  unsigned short* xc0;  // (B, 2048) bf16 recurrent state [ctx|h]
  unsigned short* xc1;
};

__device__ __forceinline__ float sigf(float v) {
  return __builtin_amdgcn_rcpf(1.0f + __expf(-v));
}
__device__ __forceinline__ float tanhfast(float v) {  // exp/rcp tanh, no libm
  float a = fabsf(v);
  float e = __expf(-2.0f * a);
  float r = (1.0f - e) * __builtin_amdgcn_rcpf(1.0f + e);
  return v < 0.0f ? -r : r;
}

__device__ __forceinline__ unsigned short f2bf(float f) {  // RNE fp32->bf16
  unsigned u = __float_as_uint(f);
  return (unsigned short)((u + 0x7FFFu + ((u >> 16) & 1u)) >> 16);
}
__device__ __forceinline__ unsigned pack2bf(float a, float b) {
  return (unsigned)f2bf(a) | ((unsigned)f2bf(b) << 16);
}
// HW packed RNE fp32->2xbf16 (same rounding as f2bf, 1 instr)
__device__ __forceinline__ unsigned cvtpk(float a, float b) {
  unsigned r;
  asm volatile("v_cvt_pk_bf16_f32 %0, %1, %2" : "=v"(r) : "v"(a), "v"(b));
  return r;
}

// Agent-scope relaxed atomics: uncached loads/stores at the LLC coherence point.
__device__ __forceinline__ void cstore_u32(unsigned* p2, unsigned v) {
  __hip_atomic_store(p2, v, __ATOMIC_RELAXED, __HIP_MEMORY_SCOPE_AGENT);
}
__device__ __forceinline__ unsigned cload_u32(const unsigned* p2) {
  return __hip_atomic_load(p2, __ATOMIC_RELAXED, __HIP_MEMORY_SCOPE_AGENT);
}
__device__ __forceinline__ unsigned long long cload_u64(const unsigned long long* p2) {
  return __hip_atomic_load(p2, __ATOMIC_RELAXED, __HIP_MEMORY_SCOPE_AGENT);
}

// LDS-only barrier: s_barrier without the vmcnt(0) drain __syncthreads implies —
// outstanding global loads ride across phase-C stage barriers.
__device__ __forceinline__ void lds_barrier() {
  asm volatile("s_waitcnt lgkmcnt(0)\n\ts_barrier" ::: "memory");
}

// ---- 2-hop split grid barrier (low poll traffic) ----
// arrive: wave 0 drains ITS OWN vmem (all exchange stores are wave-0-only by
// construction) and stores the block's flag. No full-block drain.
__device__ __forceinline__ void bar_arrive(unsigned* bar, unsigned ep, int blk,
                                           int w, int lane) {
  if (w == 0) {
    asm volatile("s_waitcnt vmcnt(0)" ::: "memory");
    if (lane == 0) cstore_u32(&bar[64 + blk * 32], ep);
  }
}
// wait: block 0's wave 0 polls all 128 flags (2 loads in flight per lane/round),
// then stores one release word; all other blocks poll the release with ONE lane.
// Poll traffic per round: 128 + 127 loads (vs 16384 in the 1-hop design).
__device__ __forceinline__ void bar_wait(unsigned* bar, unsigned ep, int blk,
                                         int w, int lane) {
  if (w == 0) {
    if (blk == 0) {
      for (;;) {
        unsigned v0 = cload_u32(&bar[64 + lane * 32]);
        unsigned v1 = cload_u32(&bar[64 + (lane + 64) * 32]);
        if (v0 >= ep && v1 >= ep) break;
        __builtin_amdgcn_s_sleep(1);
      }
      if (lane == 0) cstore_u32(&bar[0], ep);  // release
    } else if (lane == 0) {
      while (cload_u32(&bar[0]) < ep) __builtin_amdgcn_s_sleep(1);
    }
  }
  lds_barrier();  // waves 1-7 park here while wave 0 polls
}

union UF { unsigned w[4]; unsigned long long u[2]; short8 s; };

#define MFMA16 __builtin_amdgcn_mfma_f32_16x16x32_bf16

// 16 MFMAs: x-region (bfr 0-3 / 12-15) + h-region (bfr 8-11 / 20-23), 2 column-tiles.
__device__ __forceinline__ void xh_mfma(const UF* xf, const UF* hf, const short8* bfr,
                                        floatx4& a00, floatx4& a01,
                                        floatx4& a10, floatx4& a11) {
  floatx4 z = {0.f, 0.f, 0.f, 0.f};
  a00 = z; a01 = z; a10 = z; a11 = z;
  a00 = MFMA16(xf[0].s, bfr[0],  a00, 0, 0, 0); a01 = MFMA16(xf[1].s, bfr[1],  a01, 0, 0, 0);
  a10 = MFMA16(xf[0].s, bfr[12], a10, 0, 0, 0); a11 = MFMA16(xf[1].s, bfr[13], a11, 0, 0, 0);
  a00 = MFMA16(xf[2].s, bfr[2],  a00, 0, 0, 0); a01 = MFMA16(xf[3].s, bfr[3],  a01, 0, 0, 0);
  a10 = MFMA16(xf[2].s, bfr[14], a10, 0, 0, 0); a11 = MFMA16(xf[3].s, bfr[15], a11, 0, 0, 0);
  a00 = MFMA16(hf[0].s, bfr[8],  a00, 0, 0, 0); a01 = MFMA16(hf[1].s, bfr[9],  a01, 0, 0, 0);
  a10 = MFMA16(hf[0].s, bfr[20], a10, 0, 0, 0); a11 = MFMA16(hf[1].s, bfr[21], a11, 0, 0, 0);
  a00 = MFMA16(hf[2].s, bfr[10], a00, 0, 0, 0); a01 = MFMA16(hf[3].s, bfr[11], a01, 0, 0, 0);
  a10 = MFMA16(hf[2].s, bfr[22], a10, 0, 0, 0); a11 = MFMA16(hf[3].s, bfr[23], a11, 0, 0, 0);
}

__device__ __forceinline__ float sel4(const floatx4& v, int r) {  // wave-uniform r
  return (r == 0) ? v[0] : (r == 1) ? v[1] : (r == 2) ? v[2] : v[3];
}

__global__ __launch_bounds__(NTHR, 2) void tts_kernel(KParams p) {
  extern __shared__ char smem[];
  half2v* memsh2 = (half2v*)smem;  // [256 s-pairs][128 d] fp16x2, 128 KiB

  __shared__ float redC[64 * 65 + 4];     // wave-partial C tiles (8w x 2tiles x 4reg)
  __shared__ float phiP[384];             // phi wave-partials [w][48]
  __shared__ float alsh[16], ksish[16], invbsh[16];
  __shared__ float Rsh[513];              // Rsh[s+1]=R(s); Rsh[0]=R(-1)
  __shared__ half2v wsh2[256];            // w(s) packed in s-pairs
  __shared__ float ctxp[4][128];
  __shared__ float bsh48[48];             // Wg_b

  const int t    = threadIdx.x;
  const int blk  = blockIdx.x;
  const int lane = t & 63;
  const int w    = t >> 6;     // wave id [0,8): K-slice w*128 in each region
  const int bbt  = blk & 15;   // batch this block serves in phase C
  const int dc   = blk >> 4;   // [0,8): 128-wide d-chunk for ctx

  // ---- one-time: gate B-fragments (weights), 2 column-tiles x 12 chunks ----
  short8 bfr[24];
  {
    const int n = lane & 15;
    const int q = lane >> 4;
#pragma unroll
    for (int nt = 0; nt < 2; ++nt) {
      const int r = (n & 3) * 1024 + blk * 8 + nt * 4 + (n >> 2);
#pragma unroll
      for (int ki = 0; ki < 12; ++ki) {
        short8 v;
        const int k0 = (ki >> 2) * 1024 + w * 128 + (ki & 3) * 32 + q * 8;
#pragma unroll
        for (int j = 0; j < 8; ++j) {
          int k = k0 + j;
          float wv = (k < 2048) ? p.W_ih[(size_t)r * 2048 + k]
                                : p.W_hh[(size_t)r * 1024 + (k - 2048)];
          v[j] = (short)f2bf(wv);
        }
        bfr[nt * 12 + ki] = v;
      }
    }
  }
  // ---- one-time: phi B-fragments: wgB[tau*4+c] ----
  short8 wgB[12];
  {
    const int n = lane & 15;
    const int q = lane >> 4;
#pragma unroll
    for (int tau = 0; tau < 3; ++tau)
#pragma unroll
      for (int c = 0; c < 4; ++c) {
        short8 v;
        const float* wg = p.Wg_w + (size_t)(tau * 16 + n) * 1024 + w * 128 + c * 32 + q * 8;
#pragma unroll
        for (int j = 0; j < 8; ++j) v[j] = (short)f2bf(wg[j]);
        wgB[tau * 4 + c] = v;
      }
  }
  // ---- one-time: biases; wave-0 lane handles (b = lane>>2, dl = 2*(lane&3)+u) ----
  float biasreg[2][4] = {{0.f, 0.f, 0.f, 0.f}, {0.f, 0.f, 0.f, 0.f}};
  if (w == 0) {
    int b8 = 2 * (lane & 3);
#pragma unroll
    for (int u = 0; u < 2; ++u)
#pragma unroll
      for (int g = 0; g < 4; ++g) {
        int r = g * 1024 + blk * 8 + b8 + u;
        biasreg[u][g] = p.b_ih[r] + p.b_hh[r];
      }
  }
  if (t < 48) bsh48[t] = p.Wg_b[t];
  // ---- one-time: memory[bbt, :, dc*128..+128) -> LDS as half2 s-pairs ----
  {
    int dl = t & 127, sp = t >> 7;
    for (int pr = sp; pr < 256; pr += 4) {
      const float* mp = p.mem + (size_t)bbt * SS * DD + (size_t)(2 * pr) * DD + dc * 128 + dl;
      half2v v;
      v.x = (_Float16)mp[0];
      v.y = (_Float16)mp[DD];
      memsh2[pr * 128 + dl] = v;
    }
  }

  float cval[2] = {0.f, 0.f};  // LSTM cell state (wave 0: 2 dims/lane)
  unsigned ep = 0;
  unsigned short* xc_cur = p.xc0;
  unsigned short* xc_nxt = p.xc1;
  // per-lane fragment bases: A-row = batch = lane&15, k = w*128 + (lane>>4)*8
  const int ab2 = ((lane & 15) * KK2 + w * 128 + ((lane >> 4) * 8)) >> 2;  // u64 units
  const float* xrow = p.x + (size_t)(lane & 15) * TT * DD + w * 128 + ((lane >> 4) * 8);

  // Pre-loop: x_0 (direct, cacheable) + h_{-1}(=0, host-zeroed xc0) contributions.
  floatx4 acc00, acc01, acc10, acc11;
  {
    UF xf0[4], hf0[4];
#pragma unroll
    for (int sub = 0; sub < 4; ++sub) {
      floatx4 lo = *(const floatx4*)(xrow + sub * 32);
      floatx4 hi = *(const floatx4*)(xrow + sub * 32 + 4);
      xf0[sub].w[0] = cvtpk(lo[0], lo[1]); xf0[sub].w[1] = cvtpk(lo[2], lo[3]);
      xf0[sub].w[2] = cvtpk(hi[0], hi[1]); xf0[sub].w[3] = cvtpk(hi[2], hi[3]);
    }
    const unsigned long long* hb = (const unsigned long long*)p.xc0 + ab2 + 256;
#pragma unroll
    for (int sub = 0; sub < 4; ++sub) {
      hf0[sub].u[0] = cload_u64(hb + sub * 8);
      hf0[sub].u[1] = cload_u64(hb + sub * 8 + 1);
    }
    xh_mfma(xf0, hf0, bfr, acc00, acc01, acc10, acc11);
  }

  for (int tstep = 0; tstep < TT; ++tstep) {
    // ================= Phase A: ctx-part MFMA + LSTM pointwise =================
    {
      const unsigned long long* cb = (const unsigned long long*)xc_cur + ab2;
      UF fc[4];
#pragma unroll
      for (int sub = 0; sub < 4; ++sub) {
        fc[sub].u[0] = cload_u64(cb + sub * 8);
        fc[sub].u[1] = cload_u64(cb + sub * 8 + 1);
      }
      floatx4 c00 = acc00, c01 = acc01, c10 = acc10, c11 = acc11;
      c00 = MFMA16(fc[0].s, bfr[4],  c00, 0, 0, 0); c01 = MFMA16(fc[1].s, bfr[5],  c01, 0, 0, 0);
      c10 = MFMA16(fc[0].s, bfr[16], c10, 0, 0, 0); c11 = MFMA16(fc[1].s, bfr[17], c11, 0, 0, 0);
      c00 = MFMA16(fc[2].s, bfr[6],  c00, 0, 0, 0); c01 = MFMA16(fc[3].s, bfr[7],  c01, 0, 0, 0);
      c10 = MFMA16(fc[2].s, bfr[18], c10, 0, 0, 0); c11 = MFMA16(fc[3].s, bfr[19], c11, 0, 0, 0);
      c00 += c01; c10 += c11;
#pragma unroll
      for (int reg = 0; reg < 4; ++reg) {
        redC[(w * 8 + reg) * 65 + lane]     = c00[reg];
        redC[(w * 8 + 4 + reg) * 65 + lane] = c10[reg];
      }
    }
    lds_barrier();
    if (w == 0) {  // LSTM pointwise, wave 0 only: lane -> (b = lane>>2, dl = p0, p0+1)
      int b = lane >> 2, p0 = 2 * (lane & 3);
      float hv[2];
#pragma unroll
      for (int u = 0; u < 2; ++u) {
        int dl = p0 + u, nt = dl >> 2, dl4 = dl & 3;
        int row = nt * 4 + (b & 3);
        float gate[4];
#pragma unroll
        for (int g = 0; g < 4; ++g) {
          int ls = ((b >> 2) << 4) | (dl4 * 4 + g);
          float s = biasreg[u][g];
#pragma unroll
          for (int w2 = 0; w2 < 8; ++w2) s += redC[(w2 * 8 + row) * 65 + ls];
          gate[g] = s;
        }
        cval[u] = sigf(gate[1]) * cval[u] + sigf(gate[0]) * tanhfast(gate[2]);
        hv[u] = sigf(gate[3]) * tanhfast(cval[u]);
      }
      cstore_u32((unsigned*)(xc_nxt + b * KK2 + 1024 + blk * 8 + p0), pack2bf(hv[0], hv[1]));
    }
    bar_arrive(p.bar, ++ep, blk, w, lane);  // barH arrive (wave-0 vmcnt + flag)
    __builtin_amdgcn_sched_barrier(0);
    // x_{t+1} prefetch + convert (plain fp32, L2-cacheable) overlaps the barH poll
    UF xf[4];
    if (tstep + 1 < TT) {
      const float* xp = xrow + (size_t)(tstep + 1) * DD;
#pragma unroll
      for (int sub = 0; sub < 4; ++sub) {
        floatx4 lo = *(const floatx4*)(xp + sub * 32);
        floatx4 hi = *(const floatx4*)(xp + sub * 32 + 4);
        xf[sub].w[0] = cvtpk(lo[0], lo[1]); xf[sub].w[1] = cvtpk(lo[2], lo[3]);
        xf[sub].w[2] = cvtpk(hi[0], hi[1]); xf[sub].w[3] = cvtpk(hi[2], hi[3]);
      }
    }
    bar_wait(p.bar, ep, blk, w, lane);      // barH wait: h_t globally visible

    // ============ Phase C: phi(MFMA) -> softmax -> R/w -> ctx; gate MFMA rides ============
    UF hf[4];
    {
      const unsigned long long* hb = (const unsigned long long*)xc_nxt + ab2 + 256;
#pragma unroll
      for (int sub = 0; sub < 4; ++sub) {
        hf[sub].u[0] = cload_u64(hb + sub * 8);
        hf[sub].u[1] = cload_u64(hb + sub * 8 + 1);
      }
    }
    // phi = h x Wg^T via 12 MFMAs/wave (K-slice w*128..+128), D rows = batches.
    {
      floatx4 z = {0.f, 0.f, 0.f, 0.f};
      floatx4 ph0 = z, ph1 = z, ph2 = z;
      ph0 = MFMA16(hf[0].s, wgB[0], ph0, 0, 0, 0);
      ph1 = MFMA16(hf[0].s, wgB[4], ph1, 0, 0, 0);
      ph2 = MFMA16(hf[0].s, wgB[8], ph2, 0, 0, 0);
      ph0 = MFMA16(hf[1].s, wgB[1], ph0, 0, 0, 0);
      ph1 = MFMA16(hf[1].s, wgB[5], ph1, 0, 0, 0);
      ph2 = MFMA16(hf[1].s, wgB[9], ph2, 0, 0, 0);
      ph0 = MFMA16(hf[2].s, wgB[2], ph0, 0, 0, 0);
      ph1 = MFMA16(hf[2].s, wgB[6], ph1, 0, 0, 0);
      ph2 = MFMA16(hf[2].s, wgB[10], ph2, 0, 0, 0);
      ph0 = MFMA16(hf[3].s, wgB[3], ph0, 0, 0, 0);
      ph1 = MFMA16(hf[3].s, wgB[7], ph1, 0, 0, 0);
      ph2 = MFMA16(hf[3].s, wgB[11], ph2, 0, 0, 0);
      // D[m=batch][n]: lane&15 = n, (lane>>4)*4+reg = m. Keep only m = bbt.
      if ((lane >> 4) == (bbt >> 2)) {
        int m = lane & 15, r = bbt & 3;
        phiP[w * 48 + m]      = sel4(ph0, r);
        phiP[w * 48 + 16 + m] = sel4(ph1, r);
        phiP[w * 48 + 32 + m] = sel4(ph2, r);
      }
    }
    lds_barrier();
    if (w == 0) {  // merged: phi reduce + softmax + exps + R(-1), all in wave 0
      float s = 0.f;
      if (lane < 48) {
        s = bsh48[lane];
#pragma unroll
        for (int i = 0; i < 8; ++i) s += phiP[i * 48 + lane];
      }
      float mx = s;
#pragma unroll
      for (int o = 1; o < 16; o <<= 1) mx = fmaxf(mx, __shfl_xor(mx, o, 64));
      float e = __expf(s - mx);
      float sm = e;
#pragma unroll
      for (int o = 1; o < 16; o <<= 1) sm += __shfl_xor(sm, o, 64);
      float alpha_v = e * __builtin_amdgcn_rcpf(sm);
      float ksi_v   = __expf(s);
      float invb_v  = __expf(-s);
      if (lane >= 32) { if (lane < 48) alsh[lane - 32] = alpha_v; }
      else if (lane < 16) ksish[lane] = ksi_v;
      else invbsh[lane - 16] = invb_v;
      int m = lane & 15;
      float am = __shfl(alpha_v, 32 + m, 64);
      float km = __shfl(ksi_v, m, 64);
      float bm = __shfl(invb_v, 16 + m, 64);
      float term = am * sigf((-0.5f - km) * bm);
#pragma unroll
      for (int o = 1; o < 16; o <<= 1) term += __shfl_xor(term, o, 64);
      if (lane == 48) Rsh[0] = term;
    }
    lds_barrier();
    {  // R(s) + w(s)=R(s)-R(s-1) via in-wave shuffles; pack wsh2; alignment store
      float su = (float)t;
      float rv0 = 0.f, rv1 = 0.f;
#pragma unroll
      for (int m = 0; m < 16; m += 2) {
        rv0 += alsh[m]     * sigf((su + 0.5f - ksish[m])     * invbsh[m]);
        rv1 += alsh[m + 1] * sigf((su + 0.5f - ksish[m + 1]) * invbsh[m + 1]);
      }
      float rv = rv0 + rv1;
      float rvp = __shfl_up(rv, 1, 64);   // invalid at lane 0 — fixed below via Rsh
      float rvn = __shfl_down(rv, 1, 64);
      Rsh[t + 1] = rv;
      if ((t & 1) == 0) {
        half2v v2;
        v2.x = (_Float16)(rv - rvp);
        v2.y = (_Float16)(rvn - rv);
        wsh2[t >> 1] = v2;
      }
      if (dc == 0 && (t & 63) != 0)
        p.out[OUT_ALIGN + ((size_t)bbt * TT + tstep) * SS + t] = rv - rvp;
    }
    lds_barrier();
    {  // ctx partials; wave-boundary w entries (pr%32==0) recomputed from Rsh
      if (dc == 0 && t < 8)
        p.out[OUT_ALIGN + ((size_t)bbt * TT + tstep) * SS + 64 * t] =
            Rsh[64 * t + 1] - Rsh[64 * t];
      if (tstep == TT - 1 && dc == 0 && t == 0)
        p.out[OUT_TERM + bbt] = 1.0f - Rsh[p.lens[bbt]];
      int dl = t & 127, sp = t >> 7;
      const int pb = sp * 64;
      half2v wa = wsh2[pb];       wa.x = (_Float16)(Rsh[2 * pb + 1] - Rsh[2 * pb]);
      half2v wb = wsh2[pb + 32];  wb.x = (_Float16)(Rsh[2 * pb + 65] - Rsh[2 * pb + 64]);
      float s0 = __builtin_amdgcn_fdot2(memsh2[pb * 128 + dl], wa, 0.f, false);
      float s1 = __builtin_amdgcn_fdot2(memsh2[(pb + 32) * 128 + dl], wb, 0.f, false);
#pragma unroll 8
      for (int q = 1; q < 32; ++q) {
        s0 = __builtin_amdgcn_fdot2(memsh2[(pb + q) * 128 + dl],      wsh2[pb + q],      s0, false);
        s1 = __builtin_amdgcn_fdot2(memsh2[(pb + 32 + q) * 128 + dl], wsh2[pb + 32 + q], s1, false);
      }
      ctxp[sp][dl] = s0 + s1;
    }
    lds_barrier();
    if (w == 0) {  // ctx reduce (2 dims/lane) + agent store; wave-0-only vmem
      int d0 = lane * 2;
      float cv0 = ctxp[0][d0] + ctxp[1][d0] + ctxp[2][d0] + ctxp[3][d0];
      float cv1 = ctxp[0][d0 + 1] + ctxp[1][d0 + 1] + ctxp[2][d0 + 1] + ctxp[3][d0 + 1];
      if (tstep == TT - 1) {
        p.out[bbt * DD + dc * 128 + d0]     = cv0;
        p.out[bbt * DD + dc * 128 + d0 + 1] = cv1;
      }
      cstore_u32((unsigned*)(xc_nxt + bbt * KK2 + dc * 128 + d0), pack2bf(cv0, cv1));
    }
    bar_arrive(p.bar, ++ep, blk, w, lane);  // barE arrive (wave-0 vmcnt + flag)
    __builtin_amdgcn_sched_barrier(0);
    if (tstep + 1 < TT) {  // next-step x/h gate MFMAs overlap the barE poll
      xh_mfma(xf, hf, bfr, acc00, acc01, acc10, acc11);
    }
    bar_wait(p.bar, ep, blk, w, lane);      // barE wait: ctx_t globally visible

    unsigned short* tmp = xc_cur; xc_cur = xc_nxt; xc_nxt = tmp;
  }
}

extern "C" void kernel_launch(void* const* d_in, const int* in_sizes, int n_in,
                              void* d_out, int out_size, void* d_ws, size_t ws_size,
                              hipStream_t stream) {
  (void)in_sizes; (void)n_in; (void)out_size; (void)ws_size;
  KParams p;
  p.x    = (const float*)d_in[0];
  p.mem  = (const float*)d_in[1];
  p.lens = (const int*)d_in[2];
  p.W_ih = (const float*)d_in[3];
  p.W_hh = (const float*)d_in[4];
  p.b_ih = (const float*)d_in[5];
  p.b_hh = (const float*)d_in[6];
  p.Wg_w = (const float*)d_in[7];
  p.Wg_b = (const float*)d_in[8];
  p.out  = (float*)d_out;
  p.bar  = (unsigned*)d_ws;
  p.xc0  = (unsigned short*)((char*)d_ws + 36864);                  // 16*2048*2 = 64 KiB
  p.xc1  = (unsigned short*)((char*)d_ws + 36864 + 65536);

  // zero barrier flags/release + xc0 (ctx_{-1} = h_{-1} = 0)
  hipMemsetAsync(d_ws, 0, 36864 + 65536, stream);

  const unsigned dynLds = 131072;  // half2 memory slice [256][128]
  hipFuncSetAttribute((const void*)tts_kernel, hipFuncAttributeMaxDynamicSharedMemorySize,
                      (int)dynLds);

  void* args[] = { &p };
  hipLaunchCooperativeKernel((const void*)tts_kernel, dim3(NBLK), dim3(NTHR), args, dynLds,
                             stream);
}